// Round 16
// baseline (227.669 us; speedup 1.0000x reference)
//
#include <hip/hip_runtime.h>
#include <hip/hip_bf16.h>
#include <math.h>

// Problem constants (fixed by the reference)
#define BB 32      // batch
#define SS 2048    // seq len
#define DD 64      // dim_s
#define MM 32      // size_m
#define NSKILL 4096
#define CC 64      // scan chunks
#define LL 32      // chunk length = SS/CC
#define NOUT (BB * (SS - 1))   // 65504

__device__ __forceinline__ float sigmoidf_(float x) {
    return 1.f / (1.f + __expf(-x));
}
__device__ __forceinline__ float tanhf_(float x) {
    float t = __expf(-2.f * fabsf(x));
    float r = (1.f - t) / (1.f + t);
    return copysignf(r, x);
}

// ---------------------------------------------------------------------------
// Kernel 1 (k_front v5): ONE 32-token chunk per 128-thread block (2 waves).
// Same per-thread code shape as r15 (proven no-spill: VGPR 84, FETCH 11.7MB);
// only the wave->token maps shrink. LDS 41.5K -> 20.4K => ~7 blocks/CU
// (14 waves/CU, was 3 blocks/12 waves at 256thr) to lift the 21.8% occupancy
// / 57.6% VALUBusy issue-limit.
//   W  : w = softmax(k@Mk^T)   (Mk rows in VGPRs, k broadcast from LDS)
//   EA : ew[64]+aw[64] both live in ONE loop; e->e_lds, a->consumed v-row
//   C  : wave wv composes steps wv*16..+15; exchange via dead stage buffer
// ---------------------------------------------------------------------------
__global__ __launch_bounds__(128, 2) void k_front(
    const int* __restrict__ skill, const int* __restrict__ resp,
    const float* __restrict__ k_emb, const float* __restrict__ v_emb,
    const float* __restrict__ Mk,
    const float* __restrict__ eW, const float* __restrict__ eb,
    const float* __restrict__ aW, const float* __restrict__ ab,
    const float* __restrict__ mask,
    float* __restrict__ w_out, float* __restrict__ e_out, float* __restrict__ a_out,
    float* __restrict__ Abar, float* __restrict__ Bbar)
{
    __shared__ float stage[32 * 64];     // k rows -> v rows -> a vals -> xch
    __shared__ float e_lds[32 * 64];     // e vals
    __shared__ float w_lds[32 * 32];
    __shared__ float mk_lds[32];
    const int tid = threadIdx.x;
    const int g = blockIdx.x;            // chunk index = b*CC + c; tokens g*32..
    const int l = tid & 63;
    const int wv = tid >> 6;             // 0 or 1

    if (tid < 32) mk_lds[tid] = mask[g * 32 + tid];

    // ---- stage k rows (32 x 64): 8 rows per pass, 16B per thread ----
    #pragma unroll
    for (int p = 0; p < 4; ++p) {
        const int r = p * 8 + (tid >> 4);
        const int t = g * 32 + r;
        const float4 kv = ((const float4*)(k_emb + (size_t)skill[t] * DD))[tid & 15];
        *(float4*)&stage[r * 64 + (tid & 15) * 4] = kv;
    }
    __syncthreads();

    // ---- W phase: lane = (m, token-half); wave wv covers 16 tokens ----
    {
        const int m  = l & 31;
        const int th = l >> 5;
        float4 mk4[16];
        const float4* mkp = (const float4*)(Mk + m * DD);
        #pragma unroll
        for (int q = 0; q < 16; ++q) mk4[q] = mkp[q];

        for (int j = 0; j < 8; ++j) {
            const int tl = wv * 16 + j * 2 + th;       // local token 0..31
            const float4* kp = (const float4*)&stage[tl * 64];
            float a0 = 0.f, a1 = 0.f, a2 = 0.f, a3 = 0.f;
            #pragma unroll
            for (int q = 0; q < 16; ++q) {
                const float4 kv = kp[q];                 // uniform broadcast
                a0 = fmaf(kv.x, mk4[q].x, a0);
                a1 = fmaf(kv.y, mk4[q].y, a1);
                a2 = fmaf(kv.z, mk4[q].z, a2);
                a3 = fmaf(kv.w, mk4[q].w, a3);
            }
            const float lg = (a0 + a1) + (a2 + a3);
            float mx = lg;
            #pragma unroll
            for (int off = 16; off >= 1; off >>= 1) mx = fmaxf(mx, __shfl_xor(mx, off));
            const float ev = __expf(lg - mx);
            float sm = ev;
            #pragma unroll
            for (int off = 16; off >= 1; off >>= 1) sm += __shfl_xor(sm, off);
            w_lds[tl * 32 + m] = ev / sm;
        }
    }
    __syncthreads();   // w_lds complete; all waves done reading k-stage

    // coalesced global store of w (1024 floats)
    #pragma unroll
    for (int i = 0; i < 8; ++i) {
        const int idx = i * 128 + tid;
        w_out[(size_t)g * 1024 + idx] = w_lds[idx];
    }

    // ---- stage v rows (overwrite k-stage) ----
    #pragma unroll
    for (int p = 0; p < 4; ++p) {
        const int r = p * 8 + (tid >> 4);
        const int t = g * 32 + r;
        const int xc = skill[t] + NSKILL * resp[t];
        const float4 vv = ((const float4*)(v_emb + (size_t)xc * DD))[tid & 15];
        *(float4*)&stage[r * 64 + (tid & 15) * 4] = vv;
    }
    __syncthreads();

    // ---- EA phase (r15 shape): lane = d; ew/aw both live in one loop ----
    {
        float ew[64], aw[64];
        #pragma unroll
        for (int i = 0; i < 64; ++i) ew[i] = eW[i * DD + l];   // coalesced
        #pragma unroll
        for (int i = 0; i < 64; ++i) aw[i] = aW[i * DD + l];
        const float ebd = eb[l], abd = ab[l];

        for (int j = 0; j < 16; ++j) {
            const int tl = wv * 16 + j;
            const float4* vp = (const float4*)&stage[tl * 64];
            float e0 = ebd, e1 = 0.f, e2 = 0.f, e3 = 0.f;
            float x0 = abd, x1 = 0.f, x2 = 0.f, x3 = 0.f;
            #pragma unroll
            for (int q = 0; q < 16; ++q) {
                const float4 vv = vp[q];                 // uniform broadcast
                e0 = fmaf(vv.x, ew[4*q+0], e0);
                e1 = fmaf(vv.y, ew[4*q+1], e1);
                e2 = fmaf(vv.z, ew[4*q+2], e2);
                e3 = fmaf(vv.w, ew[4*q+3], e3);
                x0 = fmaf(vv.x, aw[4*q+0], x0);
                x1 = fmaf(vv.y, aw[4*q+1], x1);
                x2 = fmaf(vv.z, aw[4*q+2], x2);
                x3 = fmaf(vv.w, aw[4*q+3], x3);
            }
            const float es = sigmoidf_((e0 + e1) + (e2 + e3));
            const float as = tanhf_((x0 + x1) + (x2 + x3));
            const size_t t = (size_t)(g * 32 + tl);
            e_out[t * DD + l] = es;                      // 256B contiguous
            a_out[t * DD + l] = as;
            e_lds[tl * 64 + l] = es;
            stage[tl * 64 + l] = as;   // own row, all its reads already issued
        }
    }

    // ---- Compose phase: wave wv composes steps wv*16..+15 of this chunk ----
    float Ab[32], Bb[32];
    #pragma unroll
    for (int i = 0; i < 32; ++i) { Ab[i] = 1.f; Bb[i] = 0.f; }

    for (int j = 0; j < 16; ++j) {
        const int t = wv * 16 + j;
        const float ed = e_lds[t * 64 + l];              // lane-consecutive
        const float ad = stage[t * 64 + l];
        const float msk = (mk_lds[t] == 1.f) ? 1.f : 0.f;
        const float4* wr = (const float4*)&w_lds[t * 32];
        #pragma unroll
        for (int u = 0; u < 8; ++u) {
            float4 wq = wr[u];                           // uniform broadcast
            wq.x *= msk; wq.y *= msk; wq.z *= msk; wq.w *= msk;
            float t1;
            t1 = fmaf(-wq.x, ed, 1.f); Ab[4*u+0] *= t1; Bb[4*u+0] = fmaf(Bb[4*u+0], t1, wq.x * ad);
            t1 = fmaf(-wq.y, ed, 1.f); Ab[4*u+1] *= t1; Bb[4*u+1] = fmaf(Bb[4*u+1], t1, wq.y * ad);
            t1 = fmaf(-wq.z, ed, 1.f); Ab[4*u+2] *= t1; Bb[4*u+2] = fmaf(Bb[4*u+2], t1, wq.z * ad);
            t1 = fmaf(-wq.w, ed, 1.f); Ab[4*u+3] *= t1; Bb[4*u+3] = fmaf(Bb[4*u+3], t1, wq.w * ad);
        }
    }
    __syncthreads();   // e_lds/stage dead everywhere -> reuse as exchange buf

    // ---- exchange: wave0 (steps 0-15) publishes (Aa,Ba); wave1 combines:
    //      A = Aa*Ab, B = Ba*Ab + Bb ----
    if (wv == 0) {
        #pragma unroll
        for (int i = 0; i < 32; ++i) {
            stage[i * 64 + l]          = Ab[i];
            e_lds[i * 64 + l]          = Bb[i];
        }
    }
    __syncthreads();
    if (wv == 1) {
        const size_t base = (size_t)g * (MM * DD);
        #pragma unroll
        for (int i = 0; i < 32; ++i) {
            const float Aa = stage[i * 64 + l];
            const float Ba = e_lds[i * 64 + l];
            Abar[base + i * 64 + l] = Aa * Ab[i];                  // coalesced
            Bbar[base + i * 64 + l] = fmaf(Ba, Ab[i], Bb[i]);
        }
    }
}

// ---------------------------------------------------------------------------
// Kernel 2 (scan pass 2): sequential over 64 chunks, parallel over B*M*D.
// Unroll x8: batch 16 independent loads per 8 dependent FMAs (8 latency
// round-trips, was 16). Writes chunk-start states IN PLACE into Bbar.
// ---------------------------------------------------------------------------
__global__ __launch_bounds__(256, 2) void k_pass2(
    const float* __restrict__ Abar, float* __restrict__ Bbar_cst,
    const float* __restrict__ Mv0)
{
    const int idx = blockIdx.x * 256 + threadIdx.x;   // over B*M*D = 65536
    const int b = idx >> 11;
    const int md = idx & 2047;
    float s = Mv0[md];
    for (int c = 0; c < CC; c += 8) {
        const int o0 = ((b * CC + c) << 11) + md;
        float sa[8], sb[8];
        #pragma unroll
        for (int u = 0; u < 8; ++u) {
            sa[u] = Abar[o0 + u * 2048];
            sb[u] = Bbar_cst[o0 + u * 2048];
        }
        #pragma unroll
        for (int u = 0; u < 8; ++u) {
            Bbar_cst[o0 + u * 2048] = s;
            s = fmaf(s, sa[u], sb[u]);
        }
    }
}

// ---------------------------------------------------------------------------
// Kernel 3 (scan pass 3, d-split): 2 blocks per (b,chunk). lane=(m-half, d-off);
// Mv[16]/lane; read partials folded across m-halves with shfl_xor(32).
// ---------------------------------------------------------------------------
__global__ __launch_bounds__(64, 4) void k_pass3(
    const float* __restrict__ w, const float* __restrict__ mask,
    const float* __restrict__ e, const float* __restrict__ a,
    const float* __restrict__ cstate, float* __restrict__ readv)
{
    __shared__ float4 wl[LL * MM / 4];   // masked w  (full 32 m)
    __shared__ float4 wn[LL * MM / 4];   // unmasked w, t+1
    const int lane = threadIdx.x;
    const int bc = blockIdx.x >> 1;
    const int dh = blockIdx.x & 1;
    const int b = bc / CC;
    const int c = bc % CC;
    const int t0 = c * LL;
    const bool last = (c == CC - 1);
    const int dof = lane & 31;
    const int mh  = lane >> 5;

    const float4* wg  = (const float4*)(w + (size_t)(b * SS + t0) * MM);
    const float4* wg2 = (const float4*)(w + (size_t)(b * SS + t0 + 1) * MM);
    #pragma unroll
    for (int u = 0; u < 4; ++u) {
        const int q4 = u * 64 + lane;
        const int j = q4 >> 3;
        const float s = (mask[b * SS + t0 + j] == 1.f) ? 1.f : 0.f;
        float4 wq = wg[q4];
        wq.x *= s; wq.y *= s; wq.z *= s; wq.w *= s;
        wl[q4] = wq;
        float4 wq2;
        if (last && q4 >= 248) wq2 = make_float4(0.f, 0.f, 0.f, 0.f);
        else                   wq2 = wg2[q4];
        wn[q4] = wq2;
    }
    __syncthreads();

    float Mv[16];
    const float* cs = cstate + (size_t)bc * MM * DD + (size_t)(mh * 16) * DD
                      + dh * 32 + dof;
    #pragma unroll
    for (int i = 0; i < 16; ++i) Mv[i] = cs[i * DD];

    const float* ep = e + (size_t)(b * SS + t0) * DD + dh * 32 + dof;
    const float* ap = a + (size_t)(b * SS + t0) * DD + dh * 32 + dof;
    float* ro = readv + (size_t)(b * SS + t0 + 1) * DD + dh * 32 + dof;
    for (int j = 0; j < LL; ++j) {
        const float ed = ep[j * DD];
        const float ad = ap[j * DD];
        const float4* wlj = wl + j * 8 + mh * 4;
        const float4* wnj = wn + j * 8 + mh * 4;
        float r0 = 0.f, r1 = 0.f, r2 = 0.f, r3 = 0.f;
        #pragma unroll
        for (int u = 0; u < 4; ++u) {
            const float4 wq = wlj[u];
            const float4 w2 = wnj[u];
            float t1;
            t1 = fmaf(-wq.x, ed, 1.f); Mv[4*u+0] = fmaf(Mv[4*u+0], t1, wq.x * ad); r0 = fmaf(w2.x, Mv[4*u+0], r0);
            t1 = fmaf(-wq.y, ed, 1.f); Mv[4*u+1] = fmaf(Mv[4*u+1], t1, wq.y * ad); r1 = fmaf(w2.y, Mv[4*u+1], r1);
            t1 = fmaf(-wq.z, ed, 1.f); Mv[4*u+2] = fmaf(Mv[4*u+2], t1, wq.z * ad); r2 = fmaf(w2.z, Mv[4*u+2], r2);
            t1 = fmaf(-wq.w, ed, 1.f); Mv[4*u+3] = fmaf(Mv[4*u+3], t1, wq.w * ad); r3 = fmaf(w2.w, Mv[4*u+3], r3);
        }
        float r = (r0 + r1) + (r2 + r3);
        r += __shfl_xor(r, 32);              // fold the two m-halves
        if (mh == 0 && !(last && j == LL - 1))
            ro[j * DD] = r;
    }
}

// ---------------------------------------------------------------------------
// Kernel 4: p = tanh([read,k]@fW+fb)@pW + pb. 1024 blocks x 256 thr,
// 64 outputs/block. lane = f-column d; fW column in 128 VGPRs; read/k rows
// staged in LDS (broadcast reads); p via full-wave shfl reduce.
// ---------------------------------------------------------------------------
__global__ __launch_bounds__(256, 2) void k_final(
    const float* __restrict__ readv, const int* __restrict__ skill,
    const float* __restrict__ k_emb,
    const float* __restrict__ fW, const float* __restrict__ fb,
    const float* __restrict__ pW, const float* __restrict__ pb,
    float* __restrict__ out)
{
    __shared__ float rst[64][64];
    __shared__ float kst[64][64];
    __shared__ float pbuf[64];
    const int tid = threadIdx.x;
    const int g = blockIdx.x;
    #pragma unroll
    for (int p = 0; p < 4; ++p) {
        const int r = p * 16 + (tid >> 4);
        int o = g * 64 + r;
        if (o >= NOUT) o = 0;                       // clamp (last block only)
        const int b = o / (SS - 1);
        const int s = o - b * (SS - 1) + 1;         // 1..2047
        const size_t tok = (size_t)b * SS + s;
        const int q = tid & 15;
        *(float4*)&rst[r][q * 4] = ((const float4*)(readv + tok * DD))[q];
        *(float4*)&kst[r][q * 4] = ((const float4*)(k_emb + (size_t)skill[tok] * DD))[q];
    }
    const int l = tid & 63;
    const int w = tid >> 6;
    float fw[128];
    #pragma unroll
    for (int i = 0; i < 128; ++i) fw[i] = fW[i * DD + l];   // coalesced
    const float fbd = fb[l], pwd = pW[l];
    __syncthreads();

    for (int j = 0; j < 16; ++j) {
        const int tl = w * 16 + j;
        const float4* rp = (const float4*)&rst[tl][0];
        const float4* kp = (const float4*)&kst[tl][0];
        float f0 = fbd, f1 = 0.f, f2 = 0.f, f3 = 0.f;
        #pragma unroll
        for (int q = 0; q < 16; ++q) {
            const float4 rv = rp[q];
            f0 = fmaf(rv.x, fw[4*q+0], f0);
            f1 = fmaf(rv.y, fw[4*q+1], f1);
            f2 = fmaf(rv.z, fw[4*q+2], f2);
            f3 = fmaf(rv.w, fw[4*q+3], f3);
        }
        #pragma unroll
        for (int q = 0; q < 16; ++q) {
            const float4 kv = kp[q];
            f0 = fmaf(kv.x, fw[64+4*q+0], f0);
            f1 = fmaf(kv.y, fw[64+4*q+1], f1);
            f2 = fmaf(kv.z, fw[64+4*q+2], f2);
            f3 = fmaf(kv.w, fw[64+4*q+3], f3);
        }
        float pv = tanhf_((f0 + f1) + (f2 + f3)) * pwd;
        #pragma unroll
        for (int off = 32; off >= 1; off >>= 1) pv += __shfl_xor(pv, off);
        if (l == 0) pbuf[tl] = pv;
    }
    __syncthreads();
    if (tid < 64) {
        const int o = g * 64 + tid;
        if (o < NOUT) out[o] = pbuf[tid] + pb[0];
    }
}

// ---------------------------------------------------------------------------
extern "C" void kernel_launch(void* const* d_in, const int* in_sizes, int n_in,
                              void* d_out, int out_size, void* d_ws, size_t ws_size,
                              hipStream_t stream)
{
    const int*   response = (const int*)d_in[1];
    const int*   skill    = (const int*)d_in[2];
    const float* mask     = (const float*)d_in[3];
    const float* k_emb    = (const float*)d_in[4];
    const float* v_emb    = (const float*)d_in[5];
    const float* Mk       = (const float*)d_in[6];
    const float* Mv0      = (const float*)d_in[7];
    const float* eW       = (const float*)d_in[8];
    const float* ebias    = (const float*)d_in[9];
    const float* aW       = (const float*)d_in[10];
    const float* abias    = (const float*)d_in[11];
    const float* fW       = (const float*)d_in[12];
    const float* fbias    = (const float*)d_in[13];
    const float* pW       = (const float*)d_in[14];
    const float* pbias    = (const float*)d_in[15];
    float* out = (float*)d_out;

    // workspace layout (floats); total 23,068,672 floats = 88.0 MiB
    float* ws    = (float*)d_ws;
    float* w_    = ws;                               // B*S*M   = 2,097,152
    float* e_    = w_    + (size_t)BB * SS * MM;     // B*S*D   = 4,194,304
    float* a_    = e_    + (size_t)BB * SS * DD;
    float* Abar  = a_    + (size_t)BB * SS * DD;     // B*C*M*D = 4,194,304
    float* Bbar  = Abar  + (size_t)BB * CC * MM * DD; // doubles as cstate
    float* readv = Bbar  + (size_t)BB * CC * MM * DD; // B*S*D (row s=0 unused)

    k_front<<<BB * CC, 128, 0, stream>>>(skill, response, k_emb, v_emb, Mk,
                                         eW, ebias, aW, abias, mask,
                                         w_, e_, a_, Abar, Bbar);
    k_pass2<<<256,  256, 0, stream>>>(Abar, Bbar, Mv0);
    k_pass3<<<BB * CC * 2, 64, 0, stream>>>(w_, mask, e_, a_, Bbar, readv);
    k_final<<<1024, 256, 0, stream>>>(readv, skill, k_emb, fW, fbias,
                                      pW, pbias, out);
}